// Round 20
// baseline (239.522 us; speedup 1.0000x reference)
//
#include <hip/hip_runtime.h>
#include <hip/hip_bf16.h>
#include <math.h>

typedef unsigned short u16;
typedef __attribute__((ext_vector_type(8))) __bf16 bf16x8;
typedef __attribute__((ext_vector_type(4))) float f32x4;

#define MFMA16 __builtin_amdgcn_mfma_f32_16x16x32_bf16

__device__ __forceinline__ float bf2f(unsigned int u) {
    union { unsigned int i; float f; } x;
    x.i = (u & 0xffffu) << 16;
    return x.f;
}
__device__ __forceinline__ u16 f2bf(float f) {
    unsigned int i = __float_as_uint(f);
    unsigned int r = (i + 0x7fffu + ((i >> 16) & 1u)) >> 16;
    return (u16)r;
}

__device__ __forceinline__ void gload_lds16(const void* g, void* l) {
    __builtin_amdgcn_global_load_lds((const __attribute__((address_space(1))) void*)g,
                                     (__attribute__((address_space(3))) void*)l, 16, 0, 0);
}

// lgkm-only barrier: LDS sync without draining global loads / global_load_lds.
#define BARS() do { asm volatile("s_waitcnt lgkmcnt(0)" ::: "memory"); \
                    __builtin_amdgcn_s_barrier(); } while (0)

// ---------------------------------------------------------------- dtype detect
__global__ void detect_dtype(const unsigned* __restrict__ wq, int* __restrict__ flag)
{
    int lane = threadIdx.x;   // 64 threads
    unsigned lo = wq[lane] & 0xffffu;
    unsigned e = (lo >> 7) & 0xffu;
    int m = (e >= 0x6e && e <= 0x7e) ? 1 : 0;
#pragma unroll
    for (int s = 1; s < 64; s <<= 1) m += __shfl_xor(m, s);
    if (lane == 0) flag[0] = (m >= 32) ? 0 : 1;
}

// ---------------------------------------------------------------- prep: convert x + transpose weights (fused)
// bid < 2048: x fp32/bf16 -> bf16 (4-wide). bid >= 2048: transpose+convert the
// 4 weight matrices (exact original indexing). Two independent passes overlap.
__global__ __launch_bounds__(256) void prep(
    const void* __restrict__ x, u16* __restrict__ Xb,
    const void* __restrict__ w0, const void* __restrict__ w1,
    const void* __restrict__ w2, const void* __restrict__ w3,
    u16* __restrict__ o0, u16* __restrict__ o1,
    u16* __restrict__ o2, u16* __restrict__ o3, const int* __restrict__ flag)
{
    const int bid = blockIdx.x;
    const int tid = threadIdx.x;
    if (bid < 2048) {
        const int nchunk = 2097152;
        const int stride = 2048 * 256;
        int i0 = bid * 256 + tid;
        if (*flag) {
            const float4* s = (const float4*)x;
            for (int i = i0; i < nchunk; i += stride) {
                float4 v = s[i];
                ushort4 o;
                o.x = f2bf(v.x); o.y = f2bf(v.y); o.z = f2bf(v.z); o.w = f2bf(v.w);
                *(ushort4*)(Xb + (size_t)i * 4) = o;
            }
        } else {
            const uint2* s = (const uint2*)x;
            uint2* d = (uint2*)Xb;
            for (int i = i0; i < nchunk; i += stride) d[i] = s[i];
        }
        return;
    }
    int tb = bid - 2048;
    int z  = tb >> 9;            // 0..3
    int rem = tb & 511;
    int bx = rem & 15, by = rem >> 4;
    const void* in; u16* out;
    switch (z) {
        case 0: in = w0; out = o0; break;
        case 1: in = w1; out = o1; break;
        case 2: in = w2; out = o2; break;
        default: in = w3; out = o3; break;
    }
    int n  = bx * 64 + (tid & 63);
    int kb = by * 32 + (tid >> 6) * 8;
    u16 v[8];
    if (*flag) {
        const float* f = (const float*)in;
#pragma unroll
        for (int j = 0; j < 8; ++j) v[j] = f2bf(f[(size_t)(kb + j) * 1024 + n]);
    } else {
        const u16* s = (const u16*)in;
#pragma unroll
        for (int j = 0; j < 8; ++j) v[j] = s[(size_t)(kb + j) * 1024 + n];
    }
    uint4 pk;
    pk.x = (unsigned)v[0] | ((unsigned)v[1] << 16);
    pk.y = (unsigned)v[2] | ((unsigned)v[3] << 16);
    pk.z = (unsigned)v[4] | ((unsigned)v[5] << 16);
    pk.w = (unsigned)v[6] | ((unsigned)v[7] << 16);
    *(uint4*)(out + (size_t)n * 1024 + kb) = pk;
}

// ---------------------------------------------------------------- GEMM (BK=64, XOR-swizzled LDS)
__global__ __launch_bounds__(256) void gemm_bt(
    const u16* __restrict__ A, const u16* __restrict__ BT, void* __restrict__ C,
    int M, int Nn, int K, const int* __restrict__ flag, int fp32_out)
{
    __shared__ alignas(16) u16 As[128 * 64];   // 16 KB
    __shared__ alignas(16) u16 Bs[128 * 64];   // 16 KB
    const int tid  = threadIdx.x;
    const int lane = tid & 63;
    const int wv   = tid >> 6;
    const int wm   = wv >> 1, wn = wv & 1;
    const int bm   = blockIdx.x * 128, bn = blockIdx.y * 128;
    const int fr   = lane & 15, fk = lane >> 4;
    const int scol = ((lane & 7) ^ ((lane >> 3) & 7)) * 8;
    const int rsub = lane >> 3;

    f32x4 acc[4][4];
#pragma unroll
    for (int i = 0; i < 4; ++i)
#pragma unroll
        for (int j = 0; j < 4; ++j) acc[i][j] = (f32x4){0.f, 0.f, 0.f, 0.f};

    for (int k0 = 0; k0 < K; k0 += 64) {
        __syncthreads();
#pragma unroll
        for (int j = 0; j < 4; ++j) {
            int row = wv * 8 + j * 32 + rsub;
            gload_lds16(A  + (size_t)(bm + row) * K + k0 + scol,
                        (char*)As + (size_t)(wv * 64 + j * 256) * 16);
            gload_lds16(BT + (size_t)(bn + row) * K + k0 + scol,
                        (char*)Bs + (size_t)(wv * 64 + j * 256) * 16);
        }
        __syncthreads();
#pragma unroll
        for (int kk0 = 0; kk0 < 2; ++kk0) {
            bf16x8 af[4], bfr[4];
#pragma unroll
            for (int mi = 0; mi < 4; ++mi) {
                int R = wm * 64 + mi * 16 + fr;
                int u = (kk0 * 4 + fk) ^ (R & 7);
                af[mi] = *(const bf16x8*)(As + (size_t)R * 64 + u * 8);
            }
#pragma unroll
            for (int ni = 0; ni < 4; ++ni) {
                int R = wn * 64 + ni * 16 + fr;
                int u = (kk0 * 4 + fk) ^ (R & 7);
                bfr[ni] = *(const bf16x8*)(Bs + (size_t)R * 64 + u * 8);
            }
#pragma unroll
            for (int mi = 0; mi < 4; ++mi)
#pragma unroll
                for (int ni = 0; ni < 4; ++ni)
                    acc[mi][ni] = MFMA16(af[mi], bfr[ni], acc[mi][ni], 0, 0, 0);
        }
    }
    bool f32st = fp32_out && (*flag);
    if (f32st) {
        float* Cf = (float*)C;
#pragma unroll
        for (int mi = 0; mi < 4; ++mi)
#pragma unroll
            for (int ni = 0; ni < 4; ++ni)
#pragma unroll
                for (int j = 0; j < 4; ++j) {
                    int row = bm + wm * 64 + mi * 16 + fk * 4 + j;
                    int col = bn + wn * 64 + ni * 16 + fr;
                    Cf[(size_t)row * Nn + col] = acc[mi][ni][j];
                }
    } else {
        u16* Cb = (u16*)C;
#pragma unroll
        for (int mi = 0; mi < 4; ++mi)
#pragma unroll
            for (int ni = 0; ni < 4; ++ni)
#pragma unroll
                for (int j = 0; j < 4; ++j) {
                    int row = bm + wm * 64 + mi * 16 + fk * 4 + j;
                    int col = bn + wn * 64 + ni * 16 + fr;
                    Cb[(size_t)row * Nn + col] = f2bf(acc[mi][ni][j]);
                }
    }
}

// ---------------------------------------------------------------- fused QKV GEMM + beta
// bid < 1536: QKV GEMM (BK=64, flat grid: bx=bid%64, by=bid/64).
// bid >= 1536: beta = sigmoid(x @ Wbeta) (one wave per row, identical body).
__global__ __launch_bounds__(256) void gemm_qkv_beta(
    const u16* __restrict__ A, const u16* __restrict__ BT,
    u16* __restrict__ Qo, u16* __restrict__ Ko, u16* __restrict__ Vo,
    const void* __restrict__ Wbv, float* __restrict__ beta,
    const int* __restrict__ flag)
{
    __shared__ alignas(16) u16 As[128 * 64];
    __shared__ alignas(16) u16 Bs[128 * 64];
    const int bid = blockIdx.x;
    const int tid = threadIdx.x;
    if (bid >= 1536) {
        // ---------------- beta path
        int row  = (bid - 1536) * 4 + (tid >> 6);
        int lane = tid & 63;
        const u16* xr = A + (size_t)row * 1024;
        float a0 = 0.f, a1 = 0.f, a2 = 0.f, a3 = 0.f;
        if (*flag) {
            const float4* wf = (const float4*)Wbv;
            for (int c = 0; c < 16; ++c) {
                int k = c * 64 + lane;
                float xv = bf2f(xr[k]);
                float4 w = wf[k];
                a0 += xv * w.x; a1 += xv * w.y; a2 += xv * w.z; a3 += xv * w.w;
            }
        } else {
            const u16* wb = (const u16*)Wbv;
            for (int c = 0; c < 16; ++c) {
                int k = c * 64 + lane;
                float xv = bf2f(xr[k]);
                uint2 w = *(const uint2*)(wb + (size_t)k * 4);
                a0 += xv * bf2f(w.x);
                a1 += xv * bf2f(w.x >> 16);
                a2 += xv * bf2f(w.y);
                a3 += xv * bf2f(w.y >> 16);
            }
        }
#pragma unroll
        for (int m = 1; m < 64; m <<= 1) {
            a0 += __shfl_xor(a0, m); a1 += __shfl_xor(a1, m);
            a2 += __shfl_xor(a2, m); a3 += __shfl_xor(a3, m);
        }
        if (lane == 0) {
            int b = row >> 10, nn = row & 1023;
            beta[(size_t)(b * 4 + 0) * 1024 + nn] = 1.f / (1.f + expf(-a0));
            beta[(size_t)(b * 4 + 1) * 1024 + nn] = 1.f / (1.f + expf(-a1));
            beta[(size_t)(b * 4 + 2) * 1024 + nn] = 1.f / (1.f + expf(-a2));
            beta[(size_t)(b * 4 + 3) * 1024 + nn] = 1.f / (1.f + expf(-a3));
        }
        return;
    }
    // ---------------- QKV GEMM path
    const int lane = tid & 63;
    const int wv   = tid >> 6;
    const int wm   = wv >> 1, wn = wv & 1;
    const int bm   = (bid & 63) * 128, bn = (bid >> 6) * 128;
    const int fr   = lane & 15, fk = lane >> 4;
    const int scol = ((lane & 7) ^ ((lane >> 3) & 7)) * 8;
    const int rsub = lane >> 3;

    f32x4 acc[4][4];
#pragma unroll
    for (int i = 0; i < 4; ++i)
#pragma unroll
        for (int j = 0; j < 4; ++j) acc[i][j] = (f32x4){0.f, 0.f, 0.f, 0.f};

    for (int k0 = 0; k0 < 1024; k0 += 64) {
        __syncthreads();
#pragma unroll
        for (int j = 0; j < 4; ++j) {
            int row = wv * 8 + j * 32 + rsub;
            gload_lds16(A  + (size_t)(bm + row) * 1024 + k0 + scol,
                        (char*)As + (size_t)(wv * 64 + j * 256) * 16);
            gload_lds16(BT + (size_t)(bn + row) * 1024 + k0 + scol,
                        (char*)Bs + (size_t)(wv * 64 + j * 256) * 16);
        }
        __syncthreads();
#pragma unroll
        for (int kk0 = 0; kk0 < 2; ++kk0) {
            bf16x8 af[4], bfr[4];
#pragma unroll
            for (int mi = 0; mi < 4; ++mi) {
                int R = wm * 64 + mi * 16 + fr;
                int u = (kk0 * 4 + fk) ^ (R & 7);
                af[mi] = *(const bf16x8*)(As + (size_t)R * 64 + u * 8);
            }
#pragma unroll
            for (int ni = 0; ni < 4; ++ni) {
                int R = wn * 64 + ni * 16 + fr;
                int u = (kk0 * 4 + fk) ^ (R & 7);
                bfr[ni] = *(const bf16x8*)(Bs + (size_t)R * 64 + u * 8);
            }
#pragma unroll
            for (int mi = 0; mi < 4; ++mi)
#pragma unroll
                for (int ni = 0; ni < 4; ++ni)
                    acc[mi][ni] = MFMA16(af[mi], bfr[ni], acc[mi][ni], 0, 0, 0);
        }
    }
    const int bnn = (bid >> 6) * 128;
    const int seg = bnn >> 10;
    u16* Cb = (seg == 0) ? Qo : (seg == 1) ? Ko : Vo;
    const int cb = bnn & 1023;
#pragma unroll
    for (int mi = 0; mi < 4; ++mi)
#pragma unroll
        for (int ni = 0; ni < 4; ++ni)
#pragma unroll
            for (int j = 0; j < 4; ++j) {
                int row = bm + wm * 64 + mi * 16 + fk * 4 + j;
                int col = cb + wn * 64 + ni * 16 + fr;
                Cb[(size_t)row * 1024 + col] = f2bf(acc[mi][ni][j]);
            }
}

// ---------------------------------------------------------------- Phase A (fused: l2norm + WY precompute)
#define AP 65
__global__ __launch_bounds__(256, 2) void phaseA(
    u16* Kb, u16* Qb,
    const float* __restrict__ Bp,
    u16* __restrict__ M1hi, u16* __restrict__ M1lo,
    u16* KTg)
{
    const int bh = blockIdx.x >> 4, ch = blockIdx.x & 15;
    const int bq = bh >> 2, h = bh & 3;
    const int tid = threadIdx.x;
    const int w = tid >> 6, L = tid & 63, fr = L & 15, fk = L >> 4;

    __shared__ alignas(16) u16 Ks[64 * 264];
    __shared__ alignas(16) u16 Qs[64 * 264];
    __shared__ float bc[64];

    float* Af = (float*)Ks;                 // [64][AP] fp32 (overlay, Ks dead)
    float* Tf = (float*)(Ks + 8320);        // [64][AP] fp32
    u16* TtH = Qs;                          // [64][72] (overlay, Qs dead)
    u16* TtL = Qs + 64 * 72;
    u16* QKs = Qs + 2 * 64 * 72;            // [64][72]

    const size_t crow = ((size_t)bq * 1024 + ch * 64) * 1024 + (size_t)h * 256;
#pragma unroll
    for (int i = 0; i < 8; ++i) {
        int row = i * 8 + (tid >> 5), c8 = (tid & 31) * 8;
        const size_t ga = crow + (size_t)row * 1024 + c8;
        union { uint4 q; u16 u[8]; } KV, QV;
        KV.q = *(const uint4*)(Kb + ga);
        QV.q = *(const uint4*)(Qb + ga);
        float kf[8], qf[8], ssk = 0.f, ssq = 0.f;
#pragma unroll
        for (int e = 0; e < 8; ++e) {
            kf[e] = bf2f(KV.u[e]); ssk += kf[e] * kf[e];
            qf[e] = bf2f(QV.u[e]); ssq += qf[e] * qf[e];
        }
#pragma unroll
        for (int m = 1; m < 32; m <<= 1) {
            ssk += __shfl_xor(ssk, m);
            ssq += __shfl_xor(ssq, m);
        }
        float rk = rsqrtf(ssk + 1e-20f), rq = rsqrtf(ssq + 1e-20f);
#pragma unroll
        for (int e = 0; e < 8; ++e) {
            KV.u[e] = f2bf(kf[e] * rk);
            QV.u[e] = f2bf(qf[e] * rq);
        }
        *(uint4*)(Ks + row * 264 + c8) = KV.q;
        *(uint4*)(Qs + row * 264 + c8) = QV.q;
        *(uint4*)(Kb + ga) = KV.q;
        *(uint4*)(Qb + ga) = QV.q;
    }
    if (tid < 64) bc[tid] = Bp[(size_t)bh * 1024 + ch * 64 + tid];
    __syncthreads();

    const size_t kbase = (size_t)(bh * 16 + ch) * 16384;
#pragma unroll
    for (int i = 0; i < 8; ++i) {
        int item = tid + i * 256;
        int t = item & 63, g = item >> 6;
        union { uint4 q; u16 u[8]; } U;
        U.q = *(const uint4*)(Ks + t * 264 + g * 8);
#pragma unroll
        for (int e = 0; e < 8; ++e)
            KTg[kbase + (size_t)(g * 8 + e) * 64 + t] = U.u[e];
    }

    f32x4 kk[4], qk[4];
#pragma unroll
    for (int n = 0; n < 4; ++n) { kk[n] = (f32x4){0,0,0,0}; qk[n] = (f32x4){0,0,0,0}; }
#pragma unroll
    for (int k0 = 0; k0 < 8; ++k0) {
        bf16x8 ak = *(const bf16x8*)(Ks + (w * 16 + fr) * 264 + k0 * 32 + fk * 8);
        bf16x8 aq = *(const bf16x8*)(Qs + (w * 16 + fr) * 264 + k0 * 32 + fk * 8);
#pragma unroll
        for (int n = 0; n < 4; ++n) {
            bf16x8 bk = *(const bf16x8*)(Ks + (n * 16 + fr) * 264 + k0 * 32 + fk * 8);
            kk[n] = MFMA16(ak, bk, kk[n], 0, 0, 0);
            qk[n] = MFMA16(aq, bk, qk[n], 0, 0, 0);
        }
    }
    __syncthreads();

#pragma unroll
    for (int n = 0; n < 4; ++n)
#pragma unroll
        for (int j = 0; j < 4; ++j) {
            int t = w * 16 + fk * 4 + j, s = n * 16 + fr;
            Af[t * AP + s] = (s < t) ? bc[t] * kk[n][j] : 0.f;
            QKs[t * 72 + s] = f2bf((s <= t) ? qk[n][j] : 0.f);
        }
    for (int i = tid; i < 64 * AP; i += 256) Tf[i] = 0.f;
    __syncthreads();

    {
        int j = w * 16 + fr;
        int p = fk;
        for (int t = 0; t < 64; ++t) {
            float acc = 0.f;
#pragma unroll
            for (int i = 0; i < 16; ++i) {
                int s = p + 4 * i;
                acc += Af[t * AP + s] * Tf[s * AP + j];
            }
            acc += __shfl_xor(acc, 16);
            acc += __shfl_xor(acc, 32);
            float val = ((t == j) ? 1.f : 0.f) - acc;
            if (p == 0) Tf[t * AP + j] = val;
        }
    }
    __syncthreads();

#pragma unroll
    for (int e = 0; e < 16; ++e) {
        int idx = tid + e * 256;
        int t = idx >> 6, s = idx & 63;
        float f = Tf[t * AP + s];
        u16 hh = f2bf(f);
        TtH[s * 72 + t] = hh;
        TtL[s * 72 + t] = f2bf(f - bf2f(hh));
    }
    __syncthreads();

    const size_t tb2 = (size_t)(bh * 16 + ch) * 4096;
    f32x4 accM[4];
#pragma unroll
    for (int ns = 0; ns < 4; ++ns) accM[ns] = (f32x4){0,0,0,0};
#pragma unroll
    for (int k0 = 0; k0 < 2; ++k0) {
        bf16x8 aq = *(const bf16x8*)(QKs + (w * 16 + fr) * 72 + k0 * 32 + fk * 8);
#pragma unroll
        for (int ns = 0; ns < 4; ++ns) {
            bf16x8 bh_ = *(const bf16x8*)(TtH + (ns * 16 + fr) * 72 + k0 * 32 + fk * 8);
            bf16x8 bl_ = *(const bf16x8*)(TtL + (ns * 16 + fr) * 72 + k0 * 32 + fk * 8);
            accM[ns] = MFMA16(aq, bh_, accM[ns], 0, 0, 0);
            accM[ns] = MFMA16(aq, bl_, accM[ns], 0, 0, 0);
        }
    }
#pragma unroll
    for (int ns = 0; ns < 4; ++ns)
#pragma unroll
        for (int j = 0; j < 4; ++j) {
            int t = w * 16 + fk * 4 + j, a = ns * 16 + fr;
            float v = accM[ns][j];
            u16 hh = f2bf(v);
            M1hi[tb2 + t * 64 + a] = hh;
            M1lo[tb2 + t * 64 + a] = f2bf(v - bf2f(hh));
        }

    asm volatile("s_waitcnt vmcnt(0)" ::: "memory");
#pragma unroll
    for (int nn = 0; nn < 4; ++nn) {
        bf16x8 af2[2];
#pragma unroll
        for (int k0 = 0; k0 < 2; ++k0)
            af2[k0] = *(const bf16x8*)(KTg + kbase
                        + (size_t)(w * 64 + nn * 16 + fr) * 64 + k0 * 32 + fk * 8);
        f32x4 acc2[4];
#pragma unroll
        for (int ns = 0; ns < 4; ++ns) acc2[ns] = (f32x4){0,0,0,0};
#pragma unroll
        for (int k0 = 0; k0 < 2; ++k0)
#pragma unroll
            for (int ns = 0; ns < 4; ++ns) {
                bf16x8 bh_ = *(const bf16x8*)(TtH + (ns * 16 + fr) * 72 + k0 * 32 + fk * 8);
                bf16x8 bl_ = *(const bf16x8*)(TtL + (ns * 16 + fr) * 72 + k0 * 32 + fk * 8);
                acc2[ns] = MFMA16(af2[k0], bh_, acc2[ns], 0, 0, 0);
                acc2[ns] = MFMA16(af2[k0], bl_, acc2[ns], 0, 0, 0);
            }
        asm volatile("s_waitcnt vmcnt(0)" ::: "memory");
#pragma unroll
        for (int ns = 0; ns < 4; ++ns)
#pragma unroll
            for (int j = 0; j < 4; ++j)
                KTg[kbase + (size_t)(w * 64 + nn * 16 + fk * 4 + j) * 64 + ns * 16 + fr]
                    = f2bf(acc2[ns][j]);
    }
}

// ---------------------------------------------------------------- Phase B (chunked WY scan)
#define WTP 72
#define SHP 264
__global__ __launch_bounds__(256, 1) void phaseB(
    const u16* __restrict__ Kb, const u16* __restrict__ Qb, u16* Vb,
    const float* __restrict__ Bp,
    const u16* __restrict__ M1hi, const u16* __restrict__ M1lo,
    const u16* __restrict__ Ktil)
{
    const int bh  = blockIdx.x & 31;
    const int dvb = blockIdx.x >> 5;      // 0..7
    const int bq = bh >> 2, h = bh & 3;
    const int tid = threadIdx.x;
    const int w = tid >> 6, L = tid & 63, fr = L & 15, fk = L >> 4;
    const int rl = L >> 5, cp = L & 31;   // staging: row parity, unit

    __shared__ alignas(16) u16 Kl[64 * 256];
    __shared__ alignas(16) u16 Ql[64 * 256];
    __shared__ alignas(16) u16 S_hi[32 * SHP];
    __shared__ alignas(16) u16 S_lo[32 * SHP];
    __shared__ alignas(16) u16 W_T[32 * WTP];
    __shared__ float bc[1024];

    for (int i = tid; i < 32 * SHP; i += 256) { S_hi[i] = 0; S_lo[i] = 0; }
    for (int i = tid; i < 1024; i += 256) bc[i] = Bp[(size_t)bh * 1024 + i];

    const size_t rb = ((size_t)bq * 1024) * 1024 + (size_t)h * 256;

    f32x4 sreg[2][4];
#pragma unroll
    for (int n = 0; n < 2; ++n)
#pragma unroll
        for (int nn = 0; nn < 4; ++nn) sreg[n][nn] = (f32x4){0,0,0,0};

    bf16x8 m1h[2], m1l[2], ktf[2][4];
    u16 vr[2][4];

    auto stage_kq = [&](int c) {
        const size_t crow = rb + (size_t)(c * 64) * 1024;
#pragma unroll
        for (int i = 0; i < 8; ++i) {
            int rg = w * 16 + 2 * i + rl;
            int cu = cp ^ (rg & 7);
            gload_lds16(Kb + crow + (size_t)rg * 1024 + cu * 8,
                        (char*)Kl + (size_t)(w * 16 + 2 * i) * 512);
            gload_lds16(Qb + crow + (size_t)rg * 1024 + cu * 8,
                        (char*)Ql + (size_t)(w * 16 + 2 * i) * 512);
        }
    };
    auto pf_m1 = [&](int c) {
        const size_t mb = (size_t)(bh * 16 + c) * 4096 + (size_t)(w * 16 + fr) * 64 + fk * 8;
#pragma unroll
        for (int k0 = 0; k0 < 2; ++k0) {
            m1h[k0] = *(const bf16x8*)(M1hi + mb + k0 * 32);
            m1l[k0] = *(const bf16x8*)(M1lo + mb + k0 * 32);
        }
    };
    auto pf_ktf = [&](int c) {
        const size_t kb2 = (size_t)(bh * 16 + c) * 16384;
#pragma unroll
        for (int k0 = 0; k0 < 2; ++k0)
#pragma unroll
            for (int nn = 0; nn < 4; ++nn)
                ktf[k0][nn] = *(const bf16x8*)(Ktil + kb2
                              + (size_t)(w * 64 + nn * 16 + fr) * 64 + k0 * 32 + fk * 8);
    };
    auto pf_vr = [&](int c) {
        const size_t crow = rb + (size_t)(c * 64) * 1024;
#pragma unroll
        for (int n = 0; n < 2; ++n)
#pragma unroll
            for (int j = 0; j < 4; ++j)
                vr[n][j] = Vb[crow + (size_t)(w * 16 + fk * 4 + j) * 1024
                              + dvb * 32 + n * 16 + fr];
    };

    stage_kq(0); pf_m1(0); pf_ktf(0); pf_vr(0);
    __syncthreads();

    for (int c = 0; c < 16; ++c) {
        asm volatile("s_waitcnt vmcnt(0)" ::: "memory");
        f32x4 aPh[2], aPl[2], aOh[2], aOl[2];
#pragma unroll
        for (int n = 0; n < 2; ++n) {
            aPh[n] = (f32x4){0,0,0,0}; aPl[n] = (f32x4){0,0,0,0};
            aOh[n] = (f32x4){0,0,0,0}; aOl[n] = (f32x4){0,0,0,0};
        }
#pragma unroll
        for (int k0 = 0; k0 < 8; ++k0) {
            int ru = ((k0 * 4 + fk) ^ (fr & 7)) * 8;
            bf16x8 kqf = *(const bf16x8*)(Kl + (w * 16 + fr) * 256 + ru);
            bf16x8 qqf = *(const bf16x8*)(Ql + (w * 16 + fr) * 256 + ru);
#pragma unroll
            for (int n = 0; n < 2; ++n) {
                bf16x8 shi = *(const bf16x8*)(S_hi + (n * 16 + fr) * SHP + k0 * 32 + fk * 8);
                bf16x8 slo = *(const bf16x8*)(S_lo + (n * 16 + fr) * SHP + k0 * 32 + fk * 8);
                aPh[n] = MFMA16(kqf, shi, aPh[n], 0, 0, 0);
                aPl[n] = MFMA16(kqf, slo, aPl[n], 0, 0, 0);
                aOh[n] = MFMA16(qqf, shi, aOh[n], 0, 0, 0);
                aOl[n] = MFMA16(qqf, slo, aOl[n], 0, 0, 0);
            }
        }
        const size_t crow = rb + (size_t)(c * 64) * 1024;
#pragma unroll
        for (int n = 0; n < 2; ++n) {
            f32x4 accP = aPh[n] + aPl[n];
#pragma unroll
            for (int j = 0; j < 4; ++j) {
                int t = w * 16 + fk * 4 + j;
                W_T[(n * 16 + fr) * WTP + t] = f2bf(bc[c * 64 + t] * (bf2f(vr[n][j]) - accP[j]));
            }
        }
        if (c + 1 < 16) stage_kq(c + 1);
        BARS();
        bf16x8 wf[2][2];
#pragma unroll
        for (int n = 0; n < 2; ++n)
#pragma unroll
            for (int k0 = 0; k0 < 2; ++k0)
                wf[n][k0] = *(const bf16x8*)(W_T + (n * 16 + fr) * WTP + k0 * 32 + fk * 8);
        f32x4 accO[2];
#pragma unroll
        for (int n = 0; n < 2; ++n) {
            accO[n] = aOh[n] + aOl[n];
#pragma unroll
            for (int k0 = 0; k0 < 2; ++k0) {
                accO[n] = MFMA16(m1h[k0], wf[n][k0], accO[n], 0, 0, 0);
                accO[n] = MFMA16(m1l[k0], wf[n][k0], accO[n], 0, 0, 0);
            }
#pragma unroll
            for (int j = 0; j < 4; ++j)
                Vb[crow + (size_t)(w * 16 + fk * 4 + j) * 1024 + dvb * 32 + n * 16 + fr]
                    = f2bf(accO[n][j]);
        }
        if (c + 1 < 16) pf_m1(c + 1);
        f32x4 dS[2][4];
#pragma unroll
        for (int n = 0; n < 2; ++n)
#pragma unroll
            for (int nn = 0; nn < 4; ++nn) dS[n][nn] = (f32x4){0,0,0,0};
#pragma unroll
        for (int k0 = 0; k0 < 2; ++k0)
#pragma unroll
            for (int n = 0; n < 2; ++n)
#pragma unroll
                for (int nn = 0; nn < 4; ++nn)
                    dS[n][nn] = MFMA16(wf[n][k0], ktf[k0][nn], dS[n][nn], 0, 0, 0);
        if (c + 1 < 16) { pf_ktf(c + 1); pf_vr(c + 1); }
#pragma unroll
        for (int n = 0; n < 2; ++n)
#pragma unroll
            for (int nn = 0; nn < 4; ++nn) {
                sreg[n][nn] = sreg[n][nn] + dS[n][nn];
#pragma unroll
                for (int j = 0; j < 4; ++j) {
                    int idx = (n * 16 + fk * 4 + j) * SHP + (w * 64 + nn * 16 + fr);
                    float s = sreg[n][nn][j];
                    u16 hh = f2bf(s);
                    S_hi[idx] = hh;
                    S_lo[idx] = f2bf(s - bf2f(hh));
                }
            }
        BARS();
    }
}

// ---------------------------------------------------------------- RMSNorm over Dv, in place
__global__ __launch_bounds__(256) void rmsnorm_o(
    u16* V, const void* __restrict__ gnv, const int* __restrict__ flag)
{
    int w    = blockIdx.x * 4 + (threadIdx.x >> 6);
    int lane = threadIdx.x & 63;
    u16* p = V + (size_t)(w >> 2) * 1024 + (w & 3) * 256 + lane * 4;
    uint2 u = *(const uint2*)p;
    float f0 = bf2f(u.x), f1 = bf2f(u.x >> 16), f2 = bf2f(u.y), f3 = bf2f(u.y >> 16);
    float ss = f0 * f0 + f1 * f1 + f2 * f2 + f3 * f3;
#pragma unroll
    for (int m = 1; m < 64; m <<= 1) ss += __shfl_xor(ss, m);
    float sc = rsqrtf(ss * (1.0f / 256.0f) + 1e-5f);
    int d0 = lane * 4;
    float g0, g1, g2, g3;
    if (*flag) {
        float4 g4 = ((const float4*)gnv)[lane];
        g0 = g4.x; g1 = g4.y; g2 = g4.z; g3 = g4.w;
    } else {
        uint2 gu = *(const uint2*)((const u16*)gnv + d0);
        g0 = bf2f(gu.x); g1 = bf2f(gu.x >> 16); g2 = bf2f(gu.y); g3 = bf2f(gu.y >> 16);
    }
    uint2 o;
    o.x = (unsigned)f2bf(f0 * sc * g0) | ((unsigned)f2bf(f1 * sc * g1) << 16);
    o.y = (unsigned)f2bf(f2 * sc * g2) | ((unsigned)f2bf(f3 * sc * g3) << 16);
    *(uint2*)p = o;
}

// ---------------------------------------------------------------- launch
extern "C" void kernel_launch(void* const* d_in, const int* in_sizes, int n_in,
                              void* d_out, int out_size, void* d_ws, size_t ws_size,
                              hipStream_t stream)
{
    const void* x  = d_in[0];
    const void* Wq = d_in[1];
    const void* Wk = d_in[2];
    const void* Wv = d_in[3];
    const void* Wb = d_in[4];
    const void* Wo = d_in[5];
    const void* gn = d_in[6];

    char* ws = (char*)d_ws;
    const size_t OFF_FLAG = 0;                        // 16 KB
    const size_t OFF_XB   = OFF_FLAG + 16384;         // 16 MB (x bf16; later M1 overlay)
    const size_t OFF_WQT  = OFF_XB + 16777216;        // 2 MB (wqT/wkT/wvT contiguous)
    const size_t OFF_WKT  = OFF_WQT + 2097152;
    const size_t OFF_WVT  = OFF_WKT + 2097152;
    const size_t OFF_WOT  = OFF_WVT + 2097152;
    const size_t OFF_Q    = OFF_WOT + 2097152;        // 16 MB
    const size_t OFF_K    = OFF_Q + 16777216;         // 16 MB
    const size_t OFF_V    = OFF_K + 16777216;         // 16 MB
    const size_t OFF_BP   = OFF_V + 16777216;         // 128 KB -> ~72.6 MB

    const size_t OFF_M1H  = OFF_XB + 8388608;
    const size_t OFF_M1L  = OFF_XB + 12582912;

    int*   flag = (int*)(ws + OFF_FLAG);
    u16*   Xb   = (u16*)(ws + OFF_XB);
    u16*   wqT  = (u16*)(ws + OFF_WQT);
    u16*   wkT  = (u16*)(ws + OFF_WKT);
    u16*   wvT  = (u16*)(ws + OFF_WVT);
    u16*   woT  = (u16*)(ws + OFF_WOT);
    u16*   Qb   = (u16*)(ws + OFF_Q);
    u16*   Kb   = (u16*)(ws + OFF_K);
    u16*   Vb   = (u16*)(ws + OFF_V);
    float* Bp   = (float*)(ws + OFF_BP);
    u16*   M1hi = (u16*)(ws + OFF_M1H);
    u16*   M1lo = (u16*)(ws + OFF_M1L);
    u16*   KTg  = (u16*)d_out;   // dead until final GEMM; holds K^T then Ktil^T

    detect_dtype<<<1, 64, 0, stream>>>((const unsigned*)Wq, flag);
    prep<<<4096, 256, 0, stream>>>(x, Xb, Wq, Wk, Wv, Wo, wqT, wkT, wvT, woT, flag);
    gemm_qkv_beta<<<3584, 256, 0, stream>>>(Xb, wqT, Qb, Kb, Vb, Wb, Bp, flag);

    phaseA<<<512, 256, 0, stream>>>(Kb, Qb, Bp, M1hi, M1lo, KTg);
    phaseB<<<256, 256, 0, stream>>>(Kb, Qb, Vb, Bp, M1hi, M1lo, KTg);

    rmsnorm_o<<<8192, 256, 0, stream>>>(Vb, gn, flag);
    gemm_bt<<<dim3(64, 8), 256, 0, stream>>>(Vb, woT, d_out, 8192, 1024, 1024, flag, 1);
}

// Round 21
// 234.208 us; speedup vs baseline: 1.0227x; 1.0227x over previous
//
#include <hip/hip_runtime.h>
#include <hip/hip_bf16.h>
#include <math.h>

typedef unsigned short u16;
typedef __attribute__((ext_vector_type(8))) __bf16 bf16x8;
typedef __attribute__((ext_vector_type(4))) float f32x4;

#define MFMA16 __builtin_amdgcn_mfma_f32_16x16x32_bf16

__device__ __forceinline__ float bf2f(unsigned int u) {
    union { unsigned int i; float f; } x;
    x.i = (u & 0xffffu) << 16;
    return x.f;
}
__device__ __forceinline__ u16 f2bf(float f) {
    unsigned int i = __float_as_uint(f);
    unsigned int r = (i + 0x7fffu + ((i >> 16) & 1u)) >> 16;
    return (u16)r;
}

__device__ __forceinline__ void gload_lds16(const void* g, void* l) {
    __builtin_amdgcn_global_load_lds((const __attribute__((address_space(1))) void*)g,
                                     (__attribute__((address_space(3))) void*)l, 16, 0, 0);
}

// lgkm-only barrier: LDS sync without draining global loads / global_load_lds.
#define BARS() do { asm volatile("s_waitcnt lgkmcnt(0)" ::: "memory"); \
                    __builtin_amdgcn_s_barrier(); } while (0)

// ---------------------------------------------------------------- dtype detect
__global__ void detect_dtype(const unsigned* __restrict__ wq, int* __restrict__ flag)
{
    int lane = threadIdx.x;   // 64 threads
    unsigned lo = wq[lane] & 0xffffu;
    unsigned e = (lo >> 7) & 0xffu;
    int m = (e >= 0x6e && e <= 0x7e) ? 1 : 0;
#pragma unroll
    for (int s = 1; s < 64; s <<= 1) m += __shfl_xor(m, s);
    if (lane == 0) flag[0] = (m >= 32) ? 0 : 1;
}

// ---------------------------------------------------------------- convert x (4-wide)
__global__ __launch_bounds__(256) void convert_vec4(
    const void* __restrict__ src, u16* __restrict__ dst, int nchunk, const int* __restrict__ flag)
{
    int stride = gridDim.x * 256;
    int i0 = blockIdx.x * 256 + threadIdx.x;
    if (*flag) {
        const float4* s = (const float4*)src;
        for (int i = i0; i < nchunk; i += stride) {
            float4 v = s[i];
            ushort4 o;
            o.x = f2bf(v.x); o.y = f2bf(v.y); o.z = f2bf(v.z); o.w = f2bf(v.w);
            *(ushort4*)(dst + (size_t)i * 4) = o;
        }
    } else {
        const uint2* s = (const uint2*)src;
        uint2* d = (uint2*)dst;
        for (int i = i0; i < nchunk; i += stride) d[i] = s[i];
    }
}

// ---------------------------------------------------------------- transpose+convert
__global__ __launch_bounds__(256) void transpose_cvt(
    const void* __restrict__ w0, const void* __restrict__ w1,
    const void* __restrict__ w2, const void* __restrict__ w3,
    u16* __restrict__ o0, u16* __restrict__ o1,
    u16* __restrict__ o2, u16* __restrict__ o3, const int* __restrict__ flag)
{
    const void* in; u16* out;
    switch (blockIdx.z) {
        case 0: in = w0; out = o0; break;
        case 1: in = w1; out = o1; break;
        case 2: in = w2; out = o2; break;
        default: in = w3; out = o3; break;
    }
    int n  = blockIdx.x * 64 + (threadIdx.x & 63);
    int kb = blockIdx.y * 32 + (threadIdx.x >> 6) * 8;
    u16 v[8];
    if (*flag) {
        const float* f = (const float*)in;
#pragma unroll
        for (int j = 0; j < 8; ++j) v[j] = f2bf(f[(size_t)(kb + j) * 1024 + n]);
    } else {
        const u16* s = (const u16*)in;
#pragma unroll
        for (int j = 0; j < 8; ++j) v[j] = s[(size_t)(kb + j) * 1024 + n];
    }
    uint4 pk;
    pk.x = (unsigned)v[0] | ((unsigned)v[1] << 16);
    pk.y = (unsigned)v[2] | ((unsigned)v[3] << 16);
    pk.z = (unsigned)v[4] | ((unsigned)v[5] << 16);
    pk.w = (unsigned)v[6] | ((unsigned)v[7] << 16);
    *(uint4*)(out + (size_t)n * 1024 + kb) = pk;
}

// ---------------------------------------------------------------- GEMM (BK=64, XOR-swizzled LDS)
__global__ __launch_bounds__(256) void gemm_bt(
    const u16* __restrict__ A, const u16* __restrict__ BT, void* __restrict__ C,
    int M, int Nn, int K, const int* __restrict__ flag, int fp32_out)
{
    __shared__ alignas(16) u16 As[128 * 64];   // 16 KB
    __shared__ alignas(16) u16 Bs[128 * 64];   // 16 KB
    const int tid  = threadIdx.x;
    const int lane = tid & 63;
    const int wv   = tid >> 6;
    const int wm   = wv >> 1, wn = wv & 1;
    const int bm   = blockIdx.x * 128, bn = blockIdx.y * 128;
    const int fr   = lane & 15, fk = lane >> 4;
    const int scol = ((lane & 7) ^ ((lane >> 3) & 7)) * 8;
    const int rsub = lane >> 3;

    f32x4 acc[4][4];
#pragma unroll
    for (int i = 0; i < 4; ++i)
#pragma unroll
        for (int j = 0; j < 4; ++j) acc[i][j] = (f32x4){0.f, 0.f, 0.f, 0.f};

    for (int k0 = 0; k0 < K; k0 += 64) {
        __syncthreads();
#pragma unroll
        for (int j = 0; j < 4; ++j) {
            int row = wv * 8 + j * 32 + rsub;
            gload_lds16(A  + (size_t)(bm + row) * K + k0 + scol,
                        (char*)As + (size_t)(wv * 64 + j * 256) * 16);
            gload_lds16(BT + (size_t)(bn + row) * K + k0 + scol,
                        (char*)Bs + (size_t)(wv * 64 + j * 256) * 16);
        }
        __syncthreads();
#pragma unroll
        for (int kk0 = 0; kk0 < 2; ++kk0) {
            bf16x8 af[4], bfr[4];
#pragma unroll
            for (int mi = 0; mi < 4; ++mi) {
                int R = wm * 64 + mi * 16 + fr;
                int u = (kk0 * 4 + fk) ^ (R & 7);
                af[mi] = *(const bf16x8*)(As + (size_t)R * 64 + u * 8);
            }
#pragma unroll
            for (int ni = 0; ni < 4; ++ni) {
                int R = wn * 64 + ni * 16 + fr;
                int u = (kk0 * 4 + fk) ^ (R & 7);
                bfr[ni] = *(const bf16x8*)(Bs + (size_t)R * 64 + u * 8);
            }
#pragma unroll
            for (int mi = 0; mi < 4; ++mi)
#pragma unroll
                for (int ni = 0; ni < 4; ++ni)
                    acc[mi][ni] = MFMA16(af[mi], bfr[ni], acc[mi][ni], 0, 0, 0);
        }
    }
    bool f32st = fp32_out && (*flag);
    if (f32st) {
        float* Cf = (float*)C;
#pragma unroll
        for (int mi = 0; mi < 4; ++mi)
#pragma unroll
            for (int ni = 0; ni < 4; ++ni)
#pragma unroll
                for (int j = 0; j < 4; ++j) {
                    int row = bm + wm * 64 + mi * 16 + fk * 4 + j;
                    int col = bn + wn * 64 + ni * 16 + fr;
                    Cf[(size_t)row * Nn + col] = acc[mi][ni][j];
                }
    } else {
        u16* Cb = (u16*)C;
#pragma unroll
        for (int mi = 0; mi < 4; ++mi)
#pragma unroll
            for (int ni = 0; ni < 4; ++ni)
#pragma unroll
                for (int j = 0; j < 4; ++j) {
                    int row = bm + wm * 64 + mi * 16 + fk * 4 + j;
                    int col = bn + wn * 64 + ni * 16 + fr;
                    Cb[(size_t)row * Nn + col] = f2bf(acc[mi][ni][j]);
                }
    }
}

// ---------------------------------------------------------------- fused QKV GEMM (BK=64)
__global__ __launch_bounds__(256) void gemm_qkv(
    const u16* __restrict__ A, const u16* __restrict__ BT,
    u16* __restrict__ Qo, u16* __restrict__ Ko, u16* __restrict__ Vo)
{
    __shared__ alignas(16) u16 As[128 * 64];
    __shared__ alignas(16) u16 Bs[128 * 64];
    const int tid  = threadIdx.x;
    const int lane = tid & 63;
    const int wv   = tid >> 6;
    const int wm   = wv >> 1, wn = wv & 1;
    const int bm   = blockIdx.x * 128, bn = blockIdx.y * 128;
    const int fr   = lane & 15, fk = lane >> 4;
    const int scol = ((lane & 7) ^ ((lane >> 3) & 7)) * 8;
    const int rsub = lane >> 3;

    f32x4 acc[4][4];
#pragma unroll
    for (int i = 0; i < 4; ++i)
#pragma unroll
        for (int j = 0; j < 4; ++j) acc[i][j] = (f32x4){0.f, 0.f, 0.f, 0.f};

    for (int k0 = 0; k0 < 1024; k0 += 64) {
        __syncthreads();
#pragma unroll
        for (int j = 0; j < 4; ++j) {
            int row = wv * 8 + j * 32 + rsub;
            gload_lds16(A  + (size_t)(bm + row) * 1024 + k0 + scol,
                        (char*)As + (size_t)(wv * 64 + j * 256) * 16);
            gload_lds16(BT + (size_t)(bn + row) * 1024 + k0 + scol,
                        (char*)Bs + (size_t)(wv * 64 + j * 256) * 16);
        }
        __syncthreads();
#pragma unroll
        for (int kk0 = 0; kk0 < 2; ++kk0) {
            bf16x8 af[4], bfr[4];
#pragma unroll
            for (int mi = 0; mi < 4; ++mi) {
                int R = wm * 64 + mi * 16 + fr;
                int u = (kk0 * 4 + fk) ^ (R & 7);
                af[mi] = *(const bf16x8*)(As + (size_t)R * 64 + u * 8);
            }
#pragma unroll
            for (int ni = 0; ni < 4; ++ni) {
                int R = wn * 64 + ni * 16 + fr;
                int u = (kk0 * 4 + fk) ^ (R & 7);
                bfr[ni] = *(const bf16x8*)(Bs + (size_t)R * 64 + u * 8);
            }
#pragma unroll
            for (int mi = 0; mi < 4; ++mi)
#pragma unroll
                for (int ni = 0; ni < 4; ++ni)
                    acc[mi][ni] = MFMA16(af[mi], bfr[ni], acc[mi][ni], 0, 0, 0);
        }
    }
    const int seg = bn >> 10;
    u16* Cb = (seg == 0) ? Qo : (seg == 1) ? Ko : Vo;
    const int cb = bn & 1023;
#pragma unroll
    for (int mi = 0; mi < 4; ++mi)
#pragma unroll
        for (int ni = 0; ni < 4; ++ni)
#pragma unroll
            for (int j = 0; j < 4; ++j) {
                int row = bm + wm * 64 + mi * 16 + fk * 4 + j;
                int col = cb + wn * 64 + ni * 16 + fr;
                Cb[(size_t)row * 1024 + col] = f2bf(acc[mi][ni][j]);
            }
}

// ---------------------------------------------------------------- beta = sigmoid(x @ Wbeta)
__global__ __launch_bounds__(256) void beta_kernel(
    const u16* __restrict__ x, const void* __restrict__ Wbv,
    float* __restrict__ beta, const int* __restrict__ flag)
{
    int row  = blockIdx.x * 4 + (threadIdx.x >> 6);
    int lane = threadIdx.x & 63;
    const u16* xr = x + (size_t)row * 1024;
    float a0 = 0.f, a1 = 0.f, a2 = 0.f, a3 = 0.f;
    if (*flag) {
        const float4* wf = (const float4*)Wbv;
        for (int c = 0; c < 16; ++c) {
            int k = c * 64 + lane;
            float xv = bf2f(xr[k]);
            float4 w = wf[k];
            a0 += xv * w.x; a1 += xv * w.y; a2 += xv * w.z; a3 += xv * w.w;
        }
    } else {
        const u16* wb = (const u16*)Wbv;
        for (int c = 0; c < 16; ++c) {
            int k = c * 64 + lane;
            float xv = bf2f(xr[k]);
            uint2 w = *(const uint2*)(wb + (size_t)k * 4);
            a0 += xv * bf2f(w.x);
            a1 += xv * bf2f(w.x >> 16);
            a2 += xv * bf2f(w.y);
            a3 += xv * bf2f(w.y >> 16);
        }
    }
#pragma unroll
    for (int m = 1; m < 64; m <<= 1) {
        a0 += __shfl_xor(a0, m); a1 += __shfl_xor(a1, m);
        a2 += __shfl_xor(a2, m); a3 += __shfl_xor(a3, m);
    }
    if (lane == 0) {
        int b = row >> 10, nn = row & 1023;
        beta[(size_t)(b * 4 + 0) * 1024 + nn] = 1.f / (1.f + expf(-a0));
        beta[(size_t)(b * 4 + 1) * 1024 + nn] = 1.f / (1.f + expf(-a1));
        beta[(size_t)(b * 4 + 2) * 1024 + nn] = 1.f / (1.f + expf(-a2));
        beta[(size_t)(b * 4 + 3) * 1024 + nn] = 1.f / (1.f + expf(-a3));
    }
}

// ---------------------------------------------------------------- Phase A (fused: l2norm + WY precompute)
#define AP 65
__global__ __launch_bounds__(256, 2) void phaseA(
    u16* Kb, u16* Qb,
    const float* __restrict__ Bp,
    u16* __restrict__ M1hi, u16* __restrict__ M1lo,
    u16* KTg)
{
    const int bh = blockIdx.x >> 4, ch = blockIdx.x & 15;
    const int bq = bh >> 2, h = bh & 3;
    const int tid = threadIdx.x;
    const int w = tid >> 6, L = tid & 63, fr = L & 15, fk = L >> 4;

    __shared__ alignas(16) u16 Ks[64 * 264];
    __shared__ alignas(16) u16 Qs[64 * 264];
    __shared__ float bc[64];

    float* Af = (float*)Ks;                 // [64][AP] fp32 (overlay, Ks dead)
    float* Tf = (float*)(Ks + 8320);        // [64][AP] fp32
    u16* TtH = Qs;                          // [64][72] (overlay, Qs dead)
    u16* TtL = Qs + 64 * 72;
    u16* QKs = Qs + 2 * 64 * 72;            // [64][72]

    const size_t crow = ((size_t)bq * 1024 + ch * 64) * 1024 + (size_t)h * 256;
#pragma unroll
    for (int i = 0; i < 8; ++i) {
        int row = i * 8 + (tid >> 5), c8 = (tid & 31) * 8;
        const size_t ga = crow + (size_t)row * 1024 + c8;
        union { uint4 q; u16 u[8]; } KV, QV;
        KV.q = *(const uint4*)(Kb + ga);
        QV.q = *(const uint4*)(Qb + ga);
        float kf[8], qf[8], ssk = 0.f, ssq = 0.f;
#pragma unroll
        for (int e = 0; e < 8; ++e) {
            kf[e] = bf2f(KV.u[e]); ssk += kf[e] * kf[e];
            qf[e] = bf2f(QV.u[e]); ssq += qf[e] * qf[e];
        }
#pragma unroll
        for (int m = 1; m < 32; m <<= 1) {
            ssk += __shfl_xor(ssk, m);
            ssq += __shfl_xor(ssq, m);
        }
        float rk = rsqrtf(ssk + 1e-20f), rq = rsqrtf(ssq + 1e-20f);
#pragma unroll
        for (int e = 0; e < 8; ++e) {
            KV.u[e] = f2bf(kf[e] * rk);
            QV.u[e] = f2bf(qf[e] * rq);
        }
        *(uint4*)(Ks + row * 264 + c8) = KV.q;
        *(uint4*)(Qs + row * 264 + c8) = QV.q;
        *(uint4*)(Kb + ga) = KV.q;
        *(uint4*)(Qb + ga) = QV.q;
    }
    if (tid < 64) bc[tid] = Bp[(size_t)bh * 1024 + ch * 64 + tid];
    __syncthreads();

    const size_t kbase = (size_t)(bh * 16 + ch) * 16384;
#pragma unroll
    for (int i = 0; i < 8; ++i) {
        int item = tid + i * 256;
        int t = item & 63, g = item >> 6;
        union { uint4 q; u16 u[8]; } U;
        U.q = *(const uint4*)(Ks + t * 264 + g * 8);
#pragma unroll
        for (int e = 0; e < 8; ++e)
            KTg[kbase + (size_t)(g * 8 + e) * 64 + t] = U.u[e];
    }

    f32x4 kk[4], qk[4];
#pragma unroll
    for (int n = 0; n < 4; ++n) { kk[n] = (f32x4){0,0,0,0}; qk[n] = (f32x4){0,0,0,0}; }
#pragma unroll
    for (int k0 = 0; k0 < 8; ++k0) {
        bf16x8 ak = *(const bf16x8*)(Ks + (w * 16 + fr) * 264 + k0 * 32 + fk * 8);
        bf16x8 aq = *(const bf16x8*)(Qs + (w * 16 + fr) * 264 + k0 * 32 + fk * 8);
#pragma unroll
        for (int n = 0; n < 4; ++n) {
            bf16x8 bk = *(const bf16x8*)(Ks + (n * 16 + fr) * 264 + k0 * 32 + fk * 8);
            kk[n] = MFMA16(ak, bk, kk[n], 0, 0, 0);
            qk[n] = MFMA16(aq, bk, qk[n], 0, 0, 0);
        }
    }
    __syncthreads();

#pragma unroll
    for (int n = 0; n < 4; ++n)
#pragma unroll
        for (int j = 0; j < 4; ++j) {
            int t = w * 16 + fk * 4 + j, s = n * 16 + fr;
            Af[t * AP + s] = (s < t) ? bc[t] * kk[n][j] : 0.f;
            QKs[t * 72 + s] = f2bf((s <= t) ? qk[n][j] : 0.f);
        }
    for (int i = tid; i < 64 * AP; i += 256) Tf[i] = 0.f;
    __syncthreads();

    {
        int j = w * 16 + fr;
        int p = fk;
        for (int t = 0; t < 64; ++t) {
            float acc = 0.f;
#pragma unroll
            for (int i = 0; i < 16; ++i) {
                int s = p + 4 * i;
                acc += Af[t * AP + s] * Tf[s * AP + j];
            }
            acc += __shfl_xor(acc, 16);
            acc += __shfl_xor(acc, 32);
            float val = ((t == j) ? 1.f : 0.f) - acc;
            if (p == 0) Tf[t * AP + j] = val;
        }
    }
    __syncthreads();

#pragma unroll
    for (int e = 0; e < 16; ++e) {
        int idx = tid + e * 256;
        int t = idx >> 6, s = idx & 63;
        float f = Tf[t * AP + s];
        u16 hh = f2bf(f);
        TtH[s * 72 + t] = hh;
        TtL[s * 72 + t] = f2bf(f - bf2f(hh));
    }
    __syncthreads();

    const size_t tb2 = (size_t)(bh * 16 + ch) * 4096;
    f32x4 accM[4];
#pragma unroll
    for (int ns = 0; ns < 4; ++ns) accM[ns] = (f32x4){0,0,0,0};
#pragma unroll
    for (int k0 = 0; k0 < 2; ++k0) {
        bf16x8 aq = *(const bf16x8*)(QKs + (w * 16 + fr) * 72 + k0 * 32 + fk * 8);
#pragma unroll
        for (int ns = 0; ns < 4; ++ns) {
            bf16x8 bh_ = *(const bf16x8*)(TtH + (ns * 16 + fr) * 72 + k0 * 32 + fk * 8);
            bf16x8 bl_ = *(const bf16x8*)(TtL + (ns * 16 + fr) * 72 + k0 * 32 + fk * 8);
            accM[ns] = MFMA16(aq, bh_, accM[ns], 0, 0, 0);
            accM[ns] = MFMA16(aq, bl_, accM[ns], 0, 0, 0);
        }
    }
#pragma unroll
    for (int ns = 0; ns < 4; ++ns)
#pragma unroll
        for (int j = 0; j < 4; ++j) {
            int t = w * 16 + fk * 4 + j, a = ns * 16 + fr;
            float v = accM[ns][j];
            u16 hh = f2bf(v);
            M1hi[tb2 + t * 64 + a] = hh;
            M1lo[tb2 + t * 64 + a] = f2bf(v - bf2f(hh));
        }

    asm volatile("s_waitcnt vmcnt(0)" ::: "memory");
#pragma unroll
    for (int nn = 0; nn < 4; ++nn) {
        bf16x8 af2[2];
#pragma unroll
        for (int k0 = 0; k0 < 2; ++k0)
            af2[k0] = *(const bf16x8*)(KTg + kbase
                        + (size_t)(w * 64 + nn * 16 + fr) * 64 + k0 * 32 + fk * 8);
        f32x4 acc2[4];
#pragma unroll
        for (int ns = 0; ns < 4; ++ns) acc2[ns] = (f32x4){0,0,0,0};
#pragma unroll
        for (int k0 = 0; k0 < 2; ++k0)
#pragma unroll
            for (int ns = 0; ns < 4; ++ns) {
                bf16x8 bh_ = *(const bf16x8*)(TtH + (ns * 16 + fr) * 72 + k0 * 32 + fk * 8);
                bf16x8 bl_ = *(const bf16x8*)(TtL + (ns * 16 + fr) * 72 + k0 * 32 + fk * 8);
                acc2[ns] = MFMA16(af2[k0], bh_, acc2[ns], 0, 0, 0);
                acc2[ns] = MFMA16(af2[k0], bl_, acc2[ns], 0, 0, 0);
            }
        asm volatile("s_waitcnt vmcnt(0)" ::: "memory");
#pragma unroll
        for (int ns = 0; ns < 4; ++ns)
#pragma unroll
            for (int j = 0; j < 4; ++j)
                KTg[kbase + (size_t)(w * 64 + nn * 16 + fk * 4 + j) * 64 + ns * 16 + fr]
                    = f2bf(acc2[ns][j]);
    }
}

// ---------------------------------------------------------------- Phase B (chunked WY scan)
#define WTP 72
#define SHP 264
__global__ __launch_bounds__(256, 1) void phaseB(
    const u16* __restrict__ Kb, const u16* __restrict__ Qb, u16* Vb,
    const float* __restrict__ Bp,
    const u16* __restrict__ M1hi, const u16* __restrict__ M1lo,
    const u16* __restrict__ Ktil)
{
    const int bh  = blockIdx.x & 31;
    const int dvb = blockIdx.x >> 5;      // 0..7
    const int bq = bh >> 2, h = bh & 3;
    const int tid = threadIdx.x;
    const int w = tid >> 6, L = tid & 63, fr = L & 15, fk = L >> 4;
    const int rl = L >> 5, cp = L & 31;   // staging: row parity, unit

    __shared__ alignas(16) u16 Kl[64 * 256];
    __shared__ alignas(16) u16 Ql[64 * 256];
    __shared__ alignas(16) u16 S_hi[32 * SHP];
    __shared__ alignas(16) u16 S_lo[32 * SHP];
    __shared__ alignas(16) u16 W_T[32 * WTP];
    __shared__ float bc[1024];

    for (int i = tid; i < 32 * SHP; i += 256) { S_hi[i] = 0; S_lo[i] = 0; }
    for (int i = tid; i < 1024; i += 256) bc[i] = Bp[(size_t)bh * 1024 + i];

    const size_t rb = ((size_t)bq * 1024) * 1024 + (size_t)h * 256;

    f32x4 sreg[2][4];
#pragma unroll
    for (int n = 0; n < 2; ++n)
#pragma unroll
        for (int nn = 0; nn < 4; ++nn) sreg[n][nn] = (f32x4){0,0,0,0};

    bf16x8 m1h[2], m1l[2], ktf[2][4];
    u16 vr[2][4];

    auto stage_kq = [&](int c) {
        const size_t crow = rb + (size_t)(c * 64) * 1024;
#pragma unroll
        for (int i = 0; i < 8; ++i) {
            int rg = w * 16 + 2 * i + rl;
            int cu = cp ^ (rg & 7);
            gload_lds16(Kb + crow + (size_t)rg * 1024 + cu * 8,
                        (char*)Kl + (size_t)(w * 16 + 2 * i) * 512);
            gload_lds16(Qb + crow + (size_t)rg * 1024 + cu * 8,
                        (char*)Ql + (size_t)(w * 16 + 2 * i) * 512);
        }
    };
    auto pf_m1 = [&](int c) {
        const size_t mb = (size_t)(bh * 16 + c) * 4096 + (size_t)(w * 16 + fr) * 64 + fk * 8;
#pragma unroll
        for (int k0 = 0; k0 < 2; ++k0) {
            m1h[k0] = *(const bf16x8*)(M1hi + mb + k0 * 32);
            m1l[k0] = *(const bf16x8*)(M1lo + mb + k0 * 32);
        }
    };
    auto pf_ktf = [&](int c) {
        const size_t kb2 = (size_t)(bh * 16 + c) * 16384;
#pragma unroll
        for (int k0 = 0; k0 < 2; ++k0)
#pragma unroll
            for (int nn = 0; nn < 4; ++nn)
                ktf[k0][nn] = *(const bf16x8*)(Ktil + kb2
                              + (size_t)(w * 64 + nn * 16 + fr) * 64 + k0 * 32 + fk * 8);
    };
    auto pf_vr = [&](int c) {
        const size_t crow = rb + (size_t)(c * 64) * 1024;
#pragma unroll
        for (int n = 0; n < 2; ++n)
#pragma unroll
            for (int j = 0; j < 4; ++j)
                vr[n][j] = Vb[crow + (size_t)(w * 16 + fk * 4 + j) * 1024
                              + dvb * 32 + n * 16 + fr];
    };

    stage_kq(0); pf_m1(0); pf_ktf(0); pf_vr(0);
    __syncthreads();

    for (int c = 0; c < 16; ++c) {
        asm volatile("s_waitcnt vmcnt(0)" ::: "memory");
        f32x4 aPh[2], aPl[2], aOh[2], aOl[2];
#pragma unroll
        for (int n = 0; n < 2; ++n) {
            aPh[n] = (f32x4){0,0,0,0}; aPl[n] = (f32x4){0,0,0,0};
            aOh[n] = (f32x4){0,0,0,0}; aOl[n] = (f32x4){0,0,0,0};
        }
#pragma unroll
        for (int k0 = 0; k0 < 8; ++k0) {
            int ru = ((k0 * 4 + fk) ^ (fr & 7)) * 8;
            bf16x8 kqf = *(const bf16x8*)(Kl + (w * 16 + fr) * 256 + ru);
            bf16x8 qqf = *(const bf16x8*)(Ql + (w * 16 + fr) * 256 + ru);
#pragma unroll
            for (int n = 0; n < 2; ++n) {
                bf16x8 shi = *(const bf16x8*)(S_hi + (n * 16 + fr) * SHP + k0 * 32 + fk * 8);
                bf16x8 slo = *(const bf16x8*)(S_lo + (n * 16 + fr) * SHP + k0 * 32 + fk * 8);
                aPh[n] = MFMA16(kqf, shi, aPh[n], 0, 0, 0);
                aPl[n] = MFMA16(kqf, slo, aPl[n], 0, 0, 0);
                aOh[n] = MFMA16(qqf, shi, aOh[n], 0, 0, 0);
                aOl[n] = MFMA16(qqf, slo, aOl[n], 0, 0, 0);
            }
        }
        const size_t crow = rb + (size_t)(c * 64) * 1024;
#pragma unroll
        for (int n = 0; n < 2; ++n) {
            f32x4 accP = aPh[n] + aPl[n];
#pragma unroll
            for (int j = 0; j < 4; ++j) {
                int t = w * 16 + fk * 4 + j;
                W_T[(n * 16 + fr) * WTP + t] = f2bf(bc[c * 64 + t] * (bf2f(vr[n][j]) - accP[j]));
            }
        }
        if (c + 1 < 16) stage_kq(c + 1);
        BARS();
        bf16x8 wf[2][2];
#pragma unroll
        for (int n = 0; n < 2; ++n)
#pragma unroll
            for (int k0 = 0; k0 < 2; ++k0)
                wf[n][k0] = *(const bf16x8*)(W_T + (n * 16 + fr) * WTP + k0 * 32 + fk * 8);
        f32x4 accO[2];
#pragma unroll
        for (int n = 0; n < 2; ++n) {
            accO[n] = aOh[n] + aOl[n];
#pragma unroll
            for (int k0 = 0; k0 < 2; ++k0) {
                accO[n] = MFMA16(m1h[k0], wf[n][k0], accO[n], 0, 0, 0);
                accO[n] = MFMA16(m1l[k0], wf[n][k0], accO[n], 0, 0, 0);
            }
#pragma unroll
            for (int j = 0; j < 4; ++j)
                Vb[crow + (size_t)(w * 16 + fk * 4 + j) * 1024 + dvb * 32 + n * 16 + fr]
                    = f2bf(accO[n][j]);
        }
        if (c + 1 < 16) pf_m1(c + 1);
        f32x4 dS[2][4];
#pragma unroll
        for (int n = 0; n < 2; ++n)
#pragma unroll
            for (int nn = 0; nn < 4; ++nn) dS[n][nn] = (f32x4){0,0,0,0};
#pragma unroll
        for (int k0 = 0; k0 < 2; ++k0)
#pragma unroll
            for (int n = 0; n < 2; ++n)
#pragma unroll
                for (int nn = 0; nn < 4; ++nn)
                    dS[n][nn] = MFMA16(wf[n][k0], ktf[k0][nn], dS[n][nn], 0, 0, 0);
        if (c + 1 < 16) { pf_ktf(c + 1); pf_vr(c + 1); }
#pragma unroll
        for (int n = 0; n < 2; ++n)
#pragma unroll
            for (int nn = 0; nn < 4; ++nn) {
                sreg[n][nn] = sreg[n][nn] + dS[n][nn];
#pragma unroll
                for (int j = 0; j < 4; ++j) {
                    int idx = (n * 16 + fk * 4 + j) * SHP + (w * 64 + nn * 16 + fr);
                    float s = sreg[n][nn][j];
                    u16 hh = f2bf(s);
                    S_hi[idx] = hh;
                    S_lo[idx] = f2bf(s - bf2f(hh));
                }
            }
        BARS();
    }
}

// ---------------------------------------------------------------- RMSNorm over Dv, in place
__global__ __launch_bounds__(256) void rmsnorm_o(
    u16* V, const void* __restrict__ gnv, const int* __restrict__ flag)
{
    int w    = blockIdx.x * 4 + (threadIdx.x >> 6);
    int lane = threadIdx.x & 63;
    u16* p = V + (size_t)(w >> 2) * 1024 + (w & 3) * 256 + lane * 4;
    uint2 u = *(const uint2*)p;
    float f0 = bf2f(u.x), f1 = bf2f(u.x >> 16), f2 = bf2f(u.y), f3 = bf2f(u.y >> 16);
    float ss = f0 * f0 + f1 * f1 + f2 * f2 + f3 * f3;
#pragma unroll
    for (int m = 1; m < 64; m <<= 1) ss += __shfl_xor(ss, m);
    float sc = rsqrtf(ss * (1.0f / 256.0f) + 1e-5f);
    int d0 = lane * 4;
    float g0, g1, g2, g3;
    if (*flag) {
        float4 g4 = ((const float4*)gnv)[lane];
        g0 = g4.x; g1 = g4.y; g2 = g4.z; g3 = g4.w;
    } else {
        uint2 gu = *(const uint2*)((const u16*)gnv + d0);
        g0 = bf2f(gu.x); g1 = bf2f(gu.x >> 16); g2 = bf2f(gu.y); g3 = bf2f(gu.y >> 16);
    }
    uint2 o;
    o.x = (unsigned)f2bf(f0 * sc * g0) | ((unsigned)f2bf(f1 * sc * g1) << 16);
    o.y = (unsigned)f2bf(f2 * sc * g2) | ((unsigned)f2bf(f3 * sc * g3) << 16);
    *(uint2*)p = o;
}

// ---------------------------------------------------------------- launch
extern "C" void kernel_launch(void* const* d_in, const int* in_sizes, int n_in,
                              void* d_out, int out_size, void* d_ws, size_t ws_size,
                              hipStream_t stream)
{
    const void* x  = d_in[0];
    const void* Wq = d_in[1];
    const void* Wk = d_in[2];
    const void* Wv = d_in[3];
    const void* Wb = d_in[4];
    const void* Wo = d_in[5];
    const void* gn = d_in[6];

    char* ws = (char*)d_ws;
    const size_t OFF_FLAG = 0;                        // 16 KB
    const size_t OFF_XB   = OFF_FLAG + 16384;         // 16 MB (x bf16; later M1 overlay)
    const size_t OFF_WQT  = OFF_XB + 16777216;        // 2 MB (wqT/wkT/wvT contiguous)
    const size_t OFF_WKT  = OFF_WQT + 2097152;
    const size_t OFF_WVT  = OFF_WKT + 2097152;
    const size_t OFF_WOT  = OFF_WVT + 2097152;
    const size_t OFF_Q    = OFF_WOT + 2097152;        // 16 MB
    const size_t OFF_K    = OFF_Q + 16777216;         // 16 MB
    const size_t OFF_V    = OFF_K + 16777216;         // 16 MB
    const size_t OFF_BP   = OFF_V + 16777216;         // 128 KB -> ~72.6 MB

    const size_t OFF_M1H  = OFF_XB + 8388608;
    const size_t OFF_M1L  = OFF_XB + 12582912;

    int*   flag = (int*)(ws + OFF_FLAG);
    u16*   Xb   = (u16*)(ws + OFF_XB);
    u16*   wqT  = (u16*)(ws + OFF_WQT);
    u16*   wkT  = (u16*)(ws + OFF_WKT);
    u16*   wvT  = (u16*)(ws + OFF_WVT);
    u16*   woT  = (u16*)(ws + OFF_WOT);
    u16*   Qb   = (u16*)(ws + OFF_Q);
    u16*   Kb   = (u16*)(ws + OFF_K);
    u16*   Vb   = (u16*)(ws + OFF_V);
    float* Bp   = (float*)(ws + OFF_BP);
    u16*   M1hi = (u16*)(ws + OFF_M1H);
    u16*   M1lo = (u16*)(ws + OFF_M1L);
    u16*   KTg  = (u16*)d_out;   // dead until final GEMM; holds K^T then Ktil^T

    detect_dtype<<<1, 64, 0, stream>>>((const unsigned*)Wq, flag);
    convert_vec4<<<2048, 256, 0, stream>>>(x, Xb, 2097152, flag);
    transpose_cvt<<<dim3(16, 32, 4), 256, 0, stream>>>(Wq, Wk, Wv, Wo, wqT, wkT, wvT, woT, flag);

    gemm_qkv<<<dim3(64, 24), 256, 0, stream>>>(Xb, wqT, Qb, Kb, Vb);
    beta_kernel<<<2048, 256, 0, stream>>>(Xb, Wb, Bp, flag);

    phaseA<<<512, 256, 0, stream>>>(Kb, Qb, Bp, M1hi, M1lo, KTg);
    phaseB<<<256, 256, 0, stream>>>(Kb, Qb, Vb, Bp, M1hi, M1lo, KTg);

    rmsnorm_o<<<8192, 256, 0, stream>>>(Vb, gn, flag);
    gemm_bt<<<dim3(64, 8), 256, 0, stream>>>(Vb, woT, d_out, 8192, 1024, 1024, flag, 1);
}